// Round 11
// baseline (5836.669 us; speedup 1.0000x reference)
//
#include <hip/hip_runtime.h>
#include <math.h>
#include <stdint.h>

// ============================================================================
// TopDownNet via split-f16 MFMA, R15: R14 + fully-unrolled chunk loops.
// R14 (2340us, best): R9 skeleton + bias-in-acc + pointer-bump = 94%
// issue-busy (MfmaUtil 58.4 + VALU 35.5), occupancy 45%, no spill.
// MFMA demand is a proven floor (1.30 ms: 3 products/k/output is minimal for
// the exact 2-digit split; no f16 K=64 MFMA to fuse acc2 terms). Remaining
// lever = VALU issue count. R15: full `#pragma unroll` on all GEMM chunk
// loops -> every ds_read offset is a compile-time immediate (max 56.6KB <
// 64KB imm range) -> zero LDS-address VALU; weight addresses fold per chunk;
// scheduler may float loads across chunk boundaries within pressure budget.
// I$ ~15KB < 32KB. Abort signature (next round -> revert to R14 + declare):
// WRITE_SIZE >> 1.4GB (spill) or Occupancy ~27% (reg cap broken).
// Split math (validated R5-R14, absmax 7.6e-6): x = xh + xl*2^-11, w likewise;
//   acc1(=bias) += xh*wh ; acc2 += xh*wl + xl*wh ; result = acc1 + acc2/2048.
// Fragment layouts (gfx950 16x16x32): A row=l&15 (of), k=(l>>4)*8+i;
//   B col=l&15 (sample), same k; D row=(l>>4)*4+r, col=l&15.
// ============================================================================

typedef _Float16 half8 __attribute__((ext_vector_type(8)));
typedef __fp16 fp16x2 __attribute__((ext_vector_type(2)));  // cvt_pkrtz native
typedef float f32x4 __attribute__((ext_vector_type(4)));

constexpr int KS = 10;
constexpr int RSTR = 584;  // f16/row: 288 hi + 288 lo + 8 pad
constexpr float SPLIT_S = 2048.f;
constexpr float SPLIT_INV = 1.f / 2048.f;

// W^T fragment streams (16x16 layout, verified R5-R14).
// Frag idx within layer: f = c*16 + nt. Layer bases: O1 0, M1 144, O2 288,
// M2 416, M3 544. Frag = 64 lanes x 8 f16 (1KB).
__device__ __align__(16) _Float16 g_Wh[672 * 512];
__device__ __align__(16) _Float16 g_Wl[672 * 512];
// M1 park: 2048 blocks x 8 waves x 8 uint4 x 64 lanes (wave-private slots).
__device__ __align__(16) uint4 g_park[2048u * 8u * 8u * 64u];

__global__ void prep_w(const float* __restrict__ O1w, const float* __restrict__ M1w,
                       const float* __restrict__ O2w, const float* __restrict__ M2w,
                       const float* __restrict__ M3w) {
  const int bid = blockIdx.x, l = threadIdx.x;
  const float* W; int Ksrc, f;
  if (bid < 144)      { W = O1w; Ksrc = 270; f = bid; }
  else if (bid < 288) { W = M1w; Ksrc = 270; f = bid - 144; }
  else if (bid < 416) { W = O2w; Ksrc = 256; f = bid - 288; }
  else if (bid < 544) { W = M2w; Ksrc = 256; f = bid - 416; }
  else                { W = M3w; Ksrc = 256; f = bid - 544; }
  const int c = f >> 4, nt = f & 15, g = l >> 4, s = l & 15;
  const int of = nt * 16 + s;
  union { half8 h; uint4 u; } hv, lv;
#pragma unroll
  for (int i = 0; i < 8; ++i) {
    const int k = c * 32 + g * 8 + i;
    const float w = (k < Ksrc) ? W[k * 256 + of] : 0.f;  // zero-pad K 270..287
    const _Float16 h = (_Float16)w;
    hv.h[i] = h;
    lv.h[i] = (_Float16)((w - (float)h) * SPLIT_S);
  }
  ((uint4*)g_Wh)[bid * 64 + l] = hv.u;
  ((uint4*)g_Wl)[bid * 64 + l] = lv.u;
}

__device__ __forceinline__ half8 as_half8(uint4 u) {
  union { uint4 u4; half8 h; } c; c.u4 = u; return c.h;
}
__device__ __forceinline__ f32x4 mfma16(half8 a, half8 b, f32x4 c) {
  return __builtin_amdgcn_mfma_f32_16x16x32_f16(a, b, c, 0, 0, 0);
}
__device__ __forceinline__ uint32_t h2bits(fp16x2 h) {
  union { fp16x2 h2; uint32_t u; } c; c.h2 = h; return c.u;
}

struct PK { uint2 hi, lo; };
// RTZ split-pack of 4 f32 -> 4 f16-hi + 4 f16-lo (residual * 2048).
__device__ __forceinline__ PK split4(float v0, float v1, float v2, float v3) {
  fp16x2 h01 = __builtin_amdgcn_cvt_pkrtz(v0, v1);
  fp16x2 h23 = __builtin_amdgcn_cvt_pkrtz(v2, v3);
  fp16x2 l01 = __builtin_amdgcn_cvt_pkrtz((v0 - (float)h01[0]) * SPLIT_S,
                                          (v1 - (float)h01[1]) * SPLIT_S);
  fp16x2 l23 = __builtin_amdgcn_cvt_pkrtz((v2 - (float)h23[0]) * SPLIT_S,
                                          (v3 - (float)h23[1]) * SPLIT_S);
  PK r;
  r.hi = make_uint2(h2bits(h01), h2bits(h23));
  r.lo = make_uint2(h2bits(l01), h2bits(l23));
  return r;
}
__device__ __forceinline__ void split1(float v, _Float16& h, _Float16& l) {
  h = (_Float16)v;
  l = (_Float16)((v - (float)h) * SPLIT_S);
}

// acc1 <- layer bias (per-lane slice), acc2 <- 0.
__device__ __forceinline__ void binit24(f32x4 a1[2][4], f32x4 a2[2][4],
                                        const float* __restrict__ bias,
                                        int wu, int g) {
#pragma unroll
  for (int n = 0; n < 2; ++n) {
    const float4 bv = *(const float4*)(bias + (2 * wu + n) * 16 + 4 * g);
    const f32x4 b = {bv.x, bv.y, bv.z, bv.w};
#pragma unroll
    for (int sf = 0; sf < 4; ++sf) {
      a1[n][sf] = b;
      a2[n][sf] = (f32x4){0.f, 0.f, 0.f, 0.f};
    }
  }
}

// GEMM over CHUNKS K-chunks of 32, FULLY UNROLLED: all ds_read offsets are
// compile-time immediates off one per-lane base (Xbase = Xs + s*RSTR + g*8);
// weight addresses fold to base + chunk constants.
// Per chunk: 4 global dwordx4 + 8 ds_read_b128 + 24 MFMA, ~zero address VALU.
template <int CHUNKS>
__device__ __forceinline__ void lgemm(f32x4 a1[2][4], f32x4 a2[2][4],
                                      const _Float16* __restrict__ Xbase,
                                      const uint4* __restrict__ Wh,
                                      const uint4* __restrict__ Wl, int wu) {
  const uint4* __restrict__ wph = Wh + 2 * wu * 64;
  const uint4* __restrict__ wpl = Wl + 2 * wu * 64;
#pragma unroll
  for (int c = 0; c < CHUNKS; ++c) {
    const half8 wh0 = as_half8(wph[c * 16 * 64]);
    const half8 wh1 = as_half8(wph[c * 16 * 64 + 64]);
    const half8 wl0 = as_half8(wpl[c * 16 * 64]);
    const half8 wl1 = as_half8(wpl[c * 16 * 64 + 64]);
#pragma unroll
    for (int sf = 0; sf < 4; ++sf) {
      const _Float16* xp = Xbase + 16 * sf * RSTR + c * 32;  // all compile-time
      half8 bh = *(const half8*)xp;          // hi plane (16B aligned)
      half8 bl = *(const half8*)(xp + 288);  // lo plane
      a1[0][sf] = mfma16(wh0, bh, a1[0][sf]);
      a2[0][sf] = mfma16(wh0, bl, a2[0][sf]);
      a2[0][sf] = mfma16(wl0, bh, a2[0][sf]);
      a1[1][sf] = mfma16(wh1, bh, a1[1][sf]);
      a2[1][sf] = mfma16(wh1, bl, a2[1][sf]);
      a2[1][sf] = mfma16(wl1, bh, a2[1][sf]);
    }
  }
}

// relu(acc1 + acc2/2048) split-packed into X planes (bias already in acc1).
__device__ __forceinline__ void epi_write(const f32x4 a1[2][4], const f32x4 a2[2][4],
                                          _Float16* __restrict__ Xs,
                                          int wu, int g, int s) {
#pragma unroll
  for (int n = 0; n < 2; ++n) {
#pragma unroll
    for (int sf = 0; sf < 4; ++sf) {
      const float v0 = fmaxf(fmaf(a2[n][sf][0], SPLIT_INV, a1[n][sf][0]), 0.f);
      const float v1 = fmaxf(fmaf(a2[n][sf][1], SPLIT_INV, a1[n][sf][1]), 0.f);
      const float v2 = fmaxf(fmaf(a2[n][sf][2], SPLIT_INV, a1[n][sf][2]), 0.f);
      const float v3 = fmaxf(fmaf(a2[n][sf][3], SPLIT_INV, a1[n][sf][3]), 0.f);
      const PK p = split4(v0, v1, v2, v3);
      _Float16* yp = Xs + (16 * sf + s) * RSTR + (2 * wu + n) * 16 + 4 * g;
      *(uint2*)yp = p.hi;
      *(uint2*)(yp + 288) = p.lo;
    }
  }
}

// M1 epilogue -> coalesced park in global (wave-private slot, 8 uint4/lane).
__device__ __forceinline__ void epi_park(const f32x4 a1[2][4], const f32x4 a2[2][4],
                                         uint4* __restrict__ slot, int l) {
#pragma unroll
  for (int n = 0; n < 2; ++n) {
#pragma unroll
    for (int p = 0; p < 2; ++p) {
      PK q[2];
#pragma unroll
      for (int h = 0; h < 2; ++h) {
        const int sf = 2 * p + h;
        const float v0 = fmaxf(fmaf(a2[n][sf][0], SPLIT_INV, a1[n][sf][0]), 0.f);
        const float v1 = fmaxf(fmaf(a2[n][sf][1], SPLIT_INV, a1[n][sf][1]), 0.f);
        const float v2 = fmaxf(fmaf(a2[n][sf][2], SPLIT_INV, a1[n][sf][2]), 0.f);
        const float v3 = fmaxf(fmaf(a2[n][sf][3], SPLIT_INV, a1[n][sf][3]), 0.f);
        q[h] = split4(v0, v1, v2, v3);
      }
      slot[(n * 2 + p) * 64 + l]     = make_uint4(q[0].hi.x, q[0].hi.y, q[1].hi.x, q[1].hi.y);
      slot[(4 + n * 2 + p) * 64 + l] = make_uint4(q[0].lo.x, q[0].lo.y, q[1].lo.x, q[1].lo.y);
    }
  }
}

// unpark loaded uint4s -> X planes.
__device__ __forceinline__ void unpark_write(const uint4 pk[8],
                                             _Float16* __restrict__ Xs,
                                             int wu, int g, int s) {
#pragma unroll
  for (int n = 0; n < 2; ++n)
#pragma unroll
    for (int p = 0; p < 2; ++p) {
      const uint4 hi = pk[n * 2 + p];
      const uint4 lo = pk[4 + n * 2 + p];
#pragma unroll
      for (int h = 0; h < 2; ++h) {
        const int sf = 2 * p + h;
        _Float16* yp = Xs + (16 * sf + s) * RSTR + (2 * wu + n) * 16 + 4 * g;
        *(uint2*)yp = h ? make_uint2(hi.z, hi.w) : make_uint2(hi.x, hi.y);
        *(uint2*)(yp + 288) = h ? make_uint2(lo.z, lo.w) : make_uint2(lo.x, lo.y);
      }
    }
}

__global__ __launch_bounds__(512, 4) void topdown_mfma(
    const float* __restrict__ towers, const float* __restrict__ aggregate,
    const float* __restrict__ O1b, const float* __restrict__ O2b,
    const float* __restrict__ O3w, const float* __restrict__ O3b,
    const float* __restrict__ M1b, const float* __restrict__ M2b,
    const float* __restrict__ M3b, float* __restrict__ out) {
  __shared__ __align__(16) _Float16 Xs[64 * RSTR];  // 74752 B
  __shared__ __align__(16) float scr[64][8];        // 2 KB cross-wave reduce
  const int t = threadIdx.x, l = t & 63;
  const int wu = __builtin_amdgcn_readfirstlane(t >> 6);  // wave id = of-eighth
  const int g = l >> 4, s = l & 15;
  const int n0 = blockIdx.x * 64;
  uint4* park = g_park + ((size_t)blockIdx.x * 8 + (size_t)wu) * (8 * 64);

  // per-lane B-read base: row s, k-offset g*8 (sf/c offsets are immediates)
  const _Float16* Xbase = Xs + s * RSTR + g * 8;

  // init X: logical features 0..255 = aggregate, 256..287 = 0 (both planes).
  for (int idx = t; idx < 64 * 288; idx += 512) {
    const int ss = idx / 288, f = idx - ss * 288;
    const float v = (f < 256) ? aggregate[f] : 0.f;
    _Float16 h, lo; split1(v, h, lo);
    Xs[ss * RSTR + f] = h;
    Xs[ss * RSTR + 288 + f] = lo;
  }

  float prod = 1.f;
  const float o3bias = O3b[0];
  f32x4 a1[2][4], a2[2][4];

  const uint4* WhL = (const uint4*)g_Wh + l;
  const uint4* WlL = (const uint4*)g_Wl + l;

  for (int kk = 0; kk < KS; ++kk) {
    const int tbase = (KS - 1 - kk) * 14;  // reference flips along K
    // tower slice -> logical features 256..269 (both planes)
    for (int idx = t; idx < 64 * 14; idx += 512) {
      const int ss = idx / 14, f = idx - ss * 14;
      const float v = towers[(size_t)(n0 + ss) * (KS * 14) + tbase + f];
      _Float16 h, lo; split1(v, h, lo);
      Xs[ss * RSTR + 256 + f] = h;
      Xs[ss * RSTR + 288 + 256 + f] = lo;
    }
    __syncthreads();  // (a) towers + previous A' visible

    // ---- M1 over X=[A,T]; result -> global park
    binit24(a1, a2, M1b, wu, g);
    lgemm<9>(a1, a2, Xbase, WhL + 144 * 64, WlL + 144 * 64, wu);
    epi_park(a1, a2, park, l);

    // ---- O1 over X
    binit24(a1, a2, O1b, wu, g);
    lgemm<9>(a1, a2, Xbase, WhL, WlL, wu);
    __syncthreads();  // (b) all X reads done; park stores drained
    epi_write(a1, a2, Xs, wu, g, s);  // X[0..255] <- h1
    __syncthreads();  // (c) h1 visible

    // ---- O2 over h1 (acc1 pre-loaded with O2 bias)
    binit24(a1, a2, O2b, wu, g);
    lgemm<8>(a1, a2, Xbase, WhL + 288 * 64, WlL + 288 * 64, wu);

    // unpark loads issued now (wave-private; latency hides under O3 tail)
    asm volatile("" ::: "memory");
    uint4 pk[8];
#pragma unroll
    for (int q = 0; q < 8; ++q) pk[q] = park[q * 64 + l];

    // O3 tail: relu(O2) dot O3w -> per-sample partials (bias already in acc)
    float tq[4] = {0.f, 0.f, 0.f, 0.f};
#pragma unroll
    for (int n = 0; n < 2; ++n) {
      const int ob = (2 * wu + n) * 16 + 4 * g;
      const float4 ov = *(const float4*)(O3w + ob);
      const float oo[4] = {ov.x, ov.y, ov.z, ov.w};
#pragma unroll
      for (int sf = 0; sf < 4; ++sf)
#pragma unroll
        for (int r = 0; r < 4; ++r)
          tq[sf] += fmaxf(fmaf(a2[n][sf][r], SPLIT_INV, a1[n][sf][r]), 0.f) * oo[r];
    }
#pragma unroll
    for (int sf = 0; sf < 4; ++sf) {  // sum over the 4 g-groups
      tq[sf] += __shfl_xor(tq[sf], 16);
      tq[sf] += __shfl_xor(tq[sf], 32);
    }
    if (g == 0) {
#pragma unroll
      for (int sf = 0; sf < 4; ++sf) scr[16 * sf + s][wu] = tq[sf];
    }
    __syncthreads();  // (d) scr ready; all h1 reads done

    unpark_write(pk, Xs, wu, g, s);  // X <- A' (M1 result)
    if (t < 64) {
      const float4 s0 = *(const float4*)(scr[t]);
      const float4 s1 = *(const float4*)(scr[t] + 4);
      const float tt = ((s0.x + s0.y) + (s0.z + s0.w)) +
                       ((s1.x + s1.y) + (s1.z + s1.w)) + o3bias;
      prod *= 1.f / (1.f + expf(-tt));
    }
    __syncthreads();  // (e) A' visible

    // ---- M2 (in place)
    binit24(a1, a2, M2b, wu, g);
    lgemm<8>(a1, a2, Xbase, WhL + 416 * 64, WlL + 416 * 64, wu);
    __syncthreads();  // (f) reads done
    epi_write(a1, a2, Xs, wu, g, s);
    __syncthreads();  // (g)

    // ---- M3 (in place); next-iter sync (a) covers the write->read edge
    binit24(a1, a2, M3b, wu, g);
    lgemm<8>(a1, a2, Xbase, WhL + 544 * 64, WlL + 544 * 64, wu);
    __syncthreads();  // (h) reads done
    epi_write(a1, a2, Xs, wu, g, s);
  }

  if (t < 64) out[n0 + t] = prod;
}

extern "C" void kernel_launch(void* const* d_in, const int* in_sizes, int n_in,
                              void* d_out, int out_size, void* d_ws, size_t ws_size,
                              hipStream_t stream) {
  const float* towers    = (const float*)d_in[0];
  const float* aggregate = (const float*)d_in[1];
  const float* M1w = (const float*)d_in[2];
  const float* M1b = (const float*)d_in[3];
  const float* M2w = (const float*)d_in[4];
  const float* M2b = (const float*)d_in[5];
  const float* M3w = (const float*)d_in[6];
  const float* M3b = (const float*)d_in[7];
  const float* O1w = (const float*)d_in[8];
  const float* O1b = (const float*)d_in[9];
  const float* O2w = (const float*)d_in[10];
  const float* O2b = (const float*)d_in[11];
  const float* O3w = (const float*)d_in[12];
  const float* O3b = (const float*)d_in[13];
  float* out = (float*)d_out;

  prep_w<<<672, 64, 0, stream>>>(O1w, M1w, O2w, M2w, M3w);

  const int nblocks = out_size / 64;  // 2048 blocks x 512 threads (8 waves)
  topdown_mfma<<<nblocks, 512, 0, stream>>>(towers, aggregate, O1b, O2b, O3w,
                                            O3b, M1b, M2b, M3b, out);
}